// Round 3
// baseline (149.664 us; speedup 1.0000x reference)
//
#include <hip/hip_runtime.h>

#define B_ 4
#define H_ 12
#define N_ 1028
#define D_ 64
#define R_ 4
#define L_ 3969
#define HID_ 32
#define QBLK 64
#define KBLK 64
#define NT_ 17   // ceil(1028/64) k-tiles; also 17 q-tiles

typedef __attribute__((ext_vector_type(8))) short bf16x8;
typedef __attribute__((ext_vector_type(4))) float f32x4;
typedef __attribute__((ext_vector_type(4))) unsigned short us4;

__device__ __forceinline__ unsigned short f2bf(float f) {
  unsigned u = __builtin_bit_cast(unsigned, f);
  u += 0x7FFFu + ((u >> 16) & 1u);   // round-to-nearest-even
  return (unsigned short)(u >> 16);
}
__device__ __forceinline__ float sgnlog1p(float x) {
  float t = log1pf(fabsf(x));
  return (x > 0.f) ? t : ((x < 0.f) ? -t : 0.f);
}

// ---- tiny MLP: bt[h][l] = (gelu(rel @ W1^T + b1) @ W2^T)[l][h] ----
__global__ void bt_kernel(const float* __restrict__ rel, const float* __restrict__ W1,
                          const float* __restrict__ b1, const float* __restrict__ W2,
                          float* __restrict__ bt) {
  int l = blockIdx.x * 256 + threadIdx.x;
  if (l >= L_) return;
  float r0 = rel[2*l], r1 = rel[2*l+1];
  float hid[HID_];
#pragma unroll
  for (int j = 0; j < HID_; ++j) {
    float x = W1[2*j]*r0 + W1[2*j+1]*r1 + b1[j];
    hid[j] = 0.5f * x * (1.f + erff(x * 0.70710678118654752f)); // exact gelu
  }
#pragma unroll
  for (int h = 0; h < H_; ++h) {
    float acc = 0.f;
#pragma unroll
    for (int j = 0; j < HID_; ++j) acc += W2[h*HID_+j]*hid[j];
    bt[h*L_ + l] = acc;   // [H][L] so per-h column is contiguous
  }
}

// ---- flash attention with CPB bias (f32 in, f32 out, bf16 MFMA inside) ----
// block = 256 thr (4 waves). wave w owns q rows q0+16w .. q0+16w+15.
// S^T = mfma(A=K, B=Q): D layout col=lane&15 (=q row c), row=4g+reg (=kc). [m89]
// PV  = mfma(A=P, B=V^T): O layout col=lane&15 (=d), row=4g+reg (=q row).
__global__ __launch_bounds__(256) void attn_kernel(
    const float* __restrict__ qg, const float* __restrict__ kg_,
    const float* __restrict__ vg, const float* __restrict__ mug,
    const float* __restrict__ gammag, const float* __restrict__ btg_g,
    float* __restrict__ outg)
{
  __shared__ __align__(16) float btg[L_];                 // gamma-folded bias table, 15.9 KB
  __shared__ __align__(16) unsigned short Klds[KBLK*64];  // [kc][d] bf16, XOR-swizzled, 8 KB
  __shared__ __align__(16) unsigned short Vlds[64*KBLK];  // V^T [d][kc] bf16, swizzled, 8 KB
  __shared__ __align__(16) unsigned short Plds[4][16*64]; // per-wave P [qr][kc] bf16, 8 KB
  __shared__ __align__(16) float muk[KBLK];

  const int tid  = threadIdx.x;
  const int w    = tid >> 6;
  const int lane = tid & 63;
  const int g    = lane >> 4;
  const int c    = lane & 15;

  const int qt = blockIdx.x;        // q-tile
  const int bh = blockIdx.y;        // b*H + h
  const int b  = bh / H_;
  const int h  = bh - b*H_;
  const int q0 = qt * QBLK;

  const float gam = 1.f / (1.f + __expf(-gammag[h]));
  for (int i = tid; i < L_; i += 256) btg[i] = gam * btg_g[h*L_ + i];

  // Q fragments: f32 load -> bf16 (scale applied post-MFMA)
  const int qrow = q0 + 16*w + c;
  const int qrc  = qrow < N_ ? qrow : N_-1;
  const float* qb = qg + ((size_t)bh*N_ + qrc)*D_;
  bf16x8 qf[2];
#pragma unroll
  for (int ch = 0; ch < 2; ++ch) {
    const float* p = qb + ch*32 + g*8;
    f32x4 a0 = *(const f32x4*)p;
    f32x4 a1 = *(const f32x4*)(p+4);
    bf16x8 t;
#pragma unroll
    for (int j = 0; j < 4; ++j) { t[j] = (short)f2bf(a0[j]); t[4+j] = (short)f2bf(a1[j]); }
    qf[ch] = t;
  }
  const float muq_c = (qrow < N_) ? sgnlog1p(mug[((size_t)b*2*H_ + h)*N_ + qrow]) : 0.f;
  const int  qi  = qrow - R_;
  const bool qok = (qi >= 0) && (qrow < N_);
  const int  qy  = qi >> 5, qx = qi & 31;

  float mrun = -3.0e38f, lrun = 0.f;
  f32x4 O[4];
#pragma unroll
  for (int dt = 0; dt < 4; ++dt) O[dt] = (f32x4){0.f,0.f,0.f,0.f};

  for (int t = 0; t < NT_; ++t) {
    const int k0 = t * KBLK;
    __syncthreads();                      // prev tile's LDS reads done
    // ---- stage K [kc][d] bf16, swizzle d4 ^ ((kc&7)<<3) ----
    {
      const int kcb = tid >> 4;
      const int d4  = (tid & 15) * 4;
#pragma unroll
      for (int i = 0; i < 4; ++i) {
        int kc = kcb + i*16;
        int kr = k0 + kc; if (kr >= N_) kr = N_-1;
        f32x4 a = *(const f32x4*)(kg_ + ((size_t)bh*N_ + kr)*D_ + d4);
        us4 pb;
#pragma unroll
        for (int j = 0; j < 4; ++j) pb[j] = f2bf(a[j]);
        *(us4*)&Klds[kc*64 + (d4 ^ ((kc&7)<<3))] = pb;
      }
    }
    // ---- stage V^T [d][kc] via in-register 4x4 transpose ----
    {
      const int d0  = (tid & 15) * 4;
      const int kc0 = (tid >> 4) * 4;
      f32x4 r[4];
#pragma unroll
      for (int i = 0; i < 4; ++i) {
        int kr = k0 + kc0 + i; if (kr >= N_) kr = N_-1;
        r[i] = *(const f32x4*)(vg + ((size_t)bh*N_ + kr)*D_ + d0);
      }
#pragma unroll
      for (int j = 0; j < 4; ++j) {
        us4 pb;
#pragma unroll
        for (int i = 0; i < 4; ++i) pb[i] = f2bf(r[i][j]);
        int d = d0 + j;
        *(us4*)&Vlds[d*64 + (kc0 ^ ((d&7)<<3))] = pb;
      }
    }
    if (tid < KBLK) {
      int kr = k0 + tid;
      muk[tid] = (kr < N_) ? sgnlog1p(mug[((size_t)b*2*H_ + H_ + h)*N_ + kr]) : 0.f;
    }
    __syncthreads();                      // staging visible

    // ---- S^T tiles: 4 kc-tiles x (2 d-chunks) mfma ----
    f32x4 sc[4];
#pragma unroll
    for (int kt = 0; kt < 4; ++kt) {
      int row = kt*16 + c;
      int sw  = (row & 7) << 3;
      bf16x8 ka0 = *(const bf16x8*)&Klds[row*64 + ((g*8) ^ sw)];
      bf16x8 ka1 = *(const bf16x8*)&Klds[row*64 + ((32 + g*8) ^ sw)];
      f32x4 s = (f32x4){0.f,0.f,0.f,0.f};
      s = __builtin_amdgcn_mfma_f32_16x16x32_bf16(ka0, qf[0], s, 0, 0, 0);
      s = __builtin_amdgcn_mfma_f32_16x16x32_bf16(ka1, qf[1], s, 0, 0, 0);
      sc[kt] = s;
    }

    // ---- scale + bias + mask + row max ----
    float smax = -3.0e38f;
#pragma unroll
    for (int kt = 0; kt < 4; ++kt) {
      f32x4 mk = *(const f32x4*)&muk[kt*16 + 4*g];
      f32x4 s  = sc[kt];
#pragma unroll
      for (int r = 0; r < 4; ++r) {
        int kc    = kt*16 + 4*g + r;
        int kglob = k0 + kc;
        int ki    = kglob - R_;
        int dy = qy - (ki >> 5) + 31;
        int dx = qx - (ki & 31) + 31;
        int l  = dy*63 + dx;
        l = l < 0 ? 0 : (l > L_-1 ? L_-1 : l);
        bool ok = qok && (ki >= 0) && (kglob < N_);
        float bias = ok ? btg[l] : 0.f;
        float val  = s[r]*0.125f + (muq_c + mk[r]) * bias;
        if (kglob >= N_) val = -3.0e38f;
        s[r] = val;
        smax = fmaxf(smax, val);
      }
      sc[kt] = s;
    }
    smax = fmaxf(smax, __shfl_xor(smax, 16));
    smax = fmaxf(smax, __shfl_xor(smax, 32));
    float mnew = fmaxf(mrun, smax);
    float corr = __expf(mrun - mnew);

    // ---- exp, P->LDS (bf16), row sum ----
    float psum = 0.f;
#pragma unroll
    for (int kt = 0; kt < 4; ++kt) {
      f32x4 s = sc[kt];
      us4 pb;
#pragma unroll
      for (int r = 0; r < 4; ++r) {
        float p = __expf(s[r] - mnew);
        psum += p;
        pb[r] = f2bf(p);
      }
      *(us4*)&Plds[w][c*64 + ((kt*16 + 4*g) ^ ((c & 7) << 3))] = pb;
    }
    psum += __shfl_xor(psum, 16);
    psum += __shfl_xor(psum, 32);
    lrun = lrun * corr + psum;
    mrun = mnew;

    // ---- rescale O (corr is per q-row c; O rows are 4g+r -> shfl) ----
#pragma unroll
    for (int r = 0; r < 4; ++r) {
      float cr = __shfl(corr, 20*g + r);   // lane 16g + (4g+r): c == 4g+r
#pragma unroll
      for (int dt = 0; dt < 4; ++dt) O[dt][r] *= cr;
    }

    // order P ds_writes before P ds_reads (same wave) — rule #18 pattern
    asm volatile("s_waitcnt lgkmcnt(0)" ::: "memory");
    __builtin_amdgcn_sched_barrier(0);

    // ---- PV: O += P @ V ----
#pragma unroll
    for (int half = 0; half < 2; ++half) {
      bf16x8 pf = *(const bf16x8*)&Plds[w][c*64 + ((half*32 + g*8) ^ ((c & 7) << 3))];
#pragma unroll
      for (int dt = 0; dt < 4; ++dt) {
        int d = dt*16 + c;
        bf16x8 vf = *(const bf16x8*)&Vlds[d*64 + ((half*32 + g*8) ^ ((d & 7) << 3))];
        O[dt] = __builtin_amdgcn_mfma_f32_16x16x32_bf16(pf, vf, O[dt], 0, 0, 0);
      }
    }
  }

  // ---- epilogue: normalize + store f32 ----
  float rlv = 1.f / lrun;
#pragma unroll
  for (int r = 0; r < 4; ++r) {
    float lr = __shfl(rlv, 20*g + r);
    int qo = q0 + 16*w + 4*g + r;
    if (qo < N_) {
      float* ob = outg + ((size_t)bh*N_ + qo)*D_ + c;
#pragma unroll
      for (int dt = 0; dt < 4; ++dt) ob[dt*16] = O[dt][r] * lr;
    }
  }
}

extern "C" void kernel_launch(void* const* d_in, const int* in_sizes, int n_in,
                              void* d_out, int out_size, void* d_ws, size_t ws_size,
                              hipStream_t stream) {
  const float* q     = (const float*)d_in[0];
  const float* k     = (const float*)d_in[1];
  const float* v     = (const float*)d_in[2];
  const float* mu    = (const float*)d_in[3];
  const float* rel   = (const float*)d_in[4];
  const float* W1    = (const float*)d_in[5];
  const float* b1    = (const float*)d_in[6];
  const float* W2    = (const float*)d_in[7];
  const float* gamma = (const float*)d_in[8];
  // d_in[9] idx_table unused: index is computed analytically in-kernel.
  float* bt = (float*)d_ws;  // [H][L] = 190 KB scratch

  bt_kernel<<<dim3((L_ + 255)/256), dim3(256), 0, stream>>>(rel, W1, b1, W2, bt);
  attn_kernel<<<dim3(NT_, B_*H_), dim3(256), 0, stream>>>(q, k, v, mu, gamma, bt,
                                                          (float*)d_out);
}

// Round 5
// 82.536 us; speedup vs baseline: 1.8133x; 1.8133x over previous
//
#include <hip/hip_runtime.h>

#define B_ 4
#define H_ 12
#define N_ 1028
#define D_ 64
#define R_ 4
#define L_ 3969
#define HID_ 32
#define QBLK 64
#define KBLK 64
#define NT_ 17          // ceil(1028/64) k-tiles; also 17 q-tiles
#define NBH_ (B_*H_)    // 48
#define NWG_ (NBH_*NT_) // 816 = 8 * 102
#define LOG2E 1.4426950408889634f
#define SCL (0.125f*LOG2E)

typedef __attribute__((ext_vector_type(8))) short bf16x8;
typedef __attribute__((ext_vector_type(4))) float f32x4;
typedef __attribute__((ext_vector_type(2))) unsigned int u32x2;
typedef __attribute__((ext_vector_type(4))) unsigned int u32x4;

// RNE bf16 pair pack via HW cvt: lo -> low16, hi -> high16 (1 VALU per pair)
__device__ __forceinline__ unsigned pkbf(float lo, float hi) {
  unsigned r;
  asm("v_cvt_pk_bf16_f32 %0, %1, %2" : "=v"(r) : "v"(lo), "v"(hi));
  return r;
}
__device__ __forceinline__ float exp2_fast(float x) {
  float r; asm("v_exp_f32 %0, %1" : "=v"(r) : "v"(x)); return r;
}
__device__ __forceinline__ float sgnlog1p(float x) {
  float t = log1pf(fabsf(x));
  return (x > 0.f) ? t : ((x < 0.f) ? -t : 0.f);
}

// ---- tiny MLP: bt[h][l] = (gelu(rel @ W1^T + b1) @ W2^T)[l][h] ----
__global__ void bt_kernel(const float* __restrict__ rel, const float* __restrict__ W1,
                          const float* __restrict__ b1, const float* __restrict__ W2,
                          float* __restrict__ bt) {
  int l = blockIdx.x * 256 + threadIdx.x;
  if (l >= L_) return;
  float r0 = rel[2*l], r1 = rel[2*l+1];
  float hid[HID_];
#pragma unroll
  for (int j = 0; j < HID_; ++j) {
    float x = W1[2*j]*r0 + W1[2*j+1]*r1 + b1[j];
    hid[j] = 0.5f * x * (1.f + erff(x * 0.70710678118654752f)); // exact gelu
  }
#pragma unroll
  for (int h = 0; h < H_; ++h) {
    float acc = 0.f;
#pragma unroll
    for (int j = 0; j < HID_; ++j) acc += W2[h*HID_+j]*hid[j];
    bt[h*L_ + l] = acc;   // [H][L]
  }
}

// ---- flash attention with CPB bias; T14 reg-prefetch pipeline ----
// block = 256 thr (4 waves). wave w owns q rows q0+16w .. q0+16w+15.
// S^T = mfma(A=K, B=Q): D layout col=lane&15 (=q row c), row=4g+reg (=kc). [m89]
// PV  = mfma(A=P, B=V^T): O layout col=lane&15 (=d), row=4g+reg (=q row).
__global__ __launch_bounds__(256, 4) void attn_kernel(
    const float* __restrict__ qg, const float* __restrict__ kg_,
    const float* __restrict__ vg, const float* __restrict__ mug,
    const float* __restrict__ gammag, const float* __restrict__ btg_g,
    float* __restrict__ outg)
{
  __shared__ __align__(16) float btgs[L_ + 4];            // [0..3]=0 sentinel; [4+l]=gam*log2e*bt
  __shared__ __align__(16) unsigned short Klds[KBLK*64];  // [kc][d] bf16, XOR-swizzled
  __shared__ __align__(16) unsigned short Vlds[64*KBLK];  // V^T [d][kc] bf16, swizzled
  __shared__ __align__(16) unsigned short Plds[4][16*64]; // per-wave P [qr][kc] bf16
  __shared__ __align__(16) float muk[KBLK];

  const int tid  = threadIdx.x;
  const int w    = tid >> 6;
  const int lane = tid & 63;
  const int g    = lane >> 4;
  const int c    = lane & 15;

  // bijective XCD swizzle: 816 = 8 XCDs x 102; 102 = 6 bh-families of 17 q-tiles
  const int orig = blockIdx.x;
  const int wg   = (orig & 7) * (NWG_ / 8) + (orig >> 3);
  const int bh   = wg / NT_;
  const int qt   = wg - bh * NT_;
  const int b    = bh / H_;
  const int h    = bh - b * H_;
  const int q0   = qt * QBLK;

  const float gam  = 1.f / (1.f + __expf(-gammag[h]));
  const float gscl = gam * LOG2E;
  for (int i = tid; i < L_; i += 256) btgs[4 + i] = gscl * btg_g[h*L_ + i];
  if (tid < 4) btgs[tid] = 0.f;

  const float* qb   = qg  + (size_t)bh*N_*D_;
  const float* kb   = kg_ + (size_t)bh*N_*D_;
  const float* vb   = vg  + (size_t)bh*N_*D_;
  const float* mukp = mug + ((size_t)b*2*H_ + H_ + h)*N_;

  // Q fragments (RNE pack; scale folded post-MFMA)
  const int qrow = q0 + 16*w + c;
  const int qrc  = qrow < N_ ? qrow : N_-1;
  bf16x8 qf[2];
#pragma unroll
  for (int ch = 0; ch < 2; ++ch) {
    const float* p = qb + (size_t)qrc*D_ + ch*32 + g*8;
    f32x4 a0 = *(const f32x4*)p;
    f32x4 a1 = *(const f32x4*)(p + 4);
    u32x4 qw;
    qw[0] = pkbf(a0[0], a0[1]); qw[1] = pkbf(a0[2], a0[3]);
    qw[2] = pkbf(a1[0], a1[1]); qw[3] = pkbf(a1[2], a1[3]);
    qf[ch] = __builtin_bit_cast(bf16x8, qw);
  }
  const float muq_c = (qrow < N_) ? sgnlog1p(mug[((size_t)b*2*H_ + h)*N_ + qrow]) : 0.f;
  const int  qi  = qrow - R_;
  const bool qok = (qi >= 0) && (qrow < N_);
  const int  qy  = qi >> 5, qx = qi & 31;
  const int  lqc = qy*63 + qx + 1988;   // btgs position base (+4 sentinel, +1984 geom)

  // staging lane roles
  const int kcb  = tid >> 4;            // K rows kcb, kcb+16, ... ; 16B at d4
  const int d4   = (tid & 15) * 4;
  const int vd0  = (tid & 15) * 4;      // V: 4 rows kc0.., 16B at vd0, transposed
  const int vkc0 = (tid >> 4) * 4;

  f32x4 kpre[4], vpre[4];
  float mupre = 0.f;
  auto issue = [&](int tt) {
    const int k0n = tt * KBLK;
#pragma unroll
    for (int i = 0; i < 4; ++i) {
      int kr = k0n + kcb + i*16; if (kr >= N_) kr = N_-1;
      kpre[i] = *(const f32x4*)(kb + (size_t)kr*D_ + d4);
    }
#pragma unroll
    for (int i = 0; i < 4; ++i) {
      int kr = k0n + vkc0 + i; if (kr >= N_) kr = N_-1;
      vpre[i] = *(const f32x4*)(vb + (size_t)kr*D_ + vd0);
    }
    if (tid < KBLK) {
      int kr = k0n + tid; if (kr >= N_) kr = N_-1;
      mupre = mukp[kr];
    }
  };

  float mrun = -3.0e38f, lrun = 0.f;
  f32x4 O[4];
#pragma unroll
  for (int dt = 0; dt < 4; ++dt) O[dt] = (f32x4){0.f,0.f,0.f,0.f};

  issue(0);

  for (int t = 0; t < NT_; ++t) {
    const int k0 = t * KBLK;
    __syncthreads();        // prev-tile LDS reads done; vmcnt drains here (data needed now)
    // ---- write staged regs -> LDS ----
#pragma unroll
    for (int i = 0; i < 4; ++i) {
      int kc = kcb + i*16;
      unsigned w0 = pkbf(kpre[i][0], kpre[i][1]);
      unsigned w1 = pkbf(kpre[i][2], kpre[i][3]);
      *(u32x2*)&Klds[kc*64 + (d4 ^ ((kc & 7) << 3))] = (u32x2){w0, w1};
    }
#pragma unroll
    for (int j = 0; j < 4; ++j) {
      int d = vd0 + j;
      unsigned w0 = pkbf(vpre[0][j], vpre[1][j]);
      unsigned w1 = pkbf(vpre[2][j], vpre[3][j]);
      *(u32x2*)&Vlds[d*64 + (vkc0 ^ ((d & 7) << 3))] = (u32x2){w0, w1};
    }
    if (tid < KBLK) muk[tid] = sgnlog1p(mupre);
    __syncthreads();        // staged
    if (t + 1 < NT_) issue(t + 1);   // next tile flies during compute below

    // ---- S^T: 4 kc-subtiles x 2 d-chunks ----
    f32x4 sc[4];
#pragma unroll
    for (int kt = 0; kt < 4; ++kt) {
      int row = kt*16 + c;
      int sw  = (row & 7) << 3;
      bf16x8 ka0 = *(const bf16x8*)&Klds[row*64 + ((g*8) ^ sw)];
      bf16x8 ka1 = *(const bf16x8*)&Klds[row*64 + ((32 + g*8) ^ sw)];
      f32x4 s = (f32x4){0.f,0.f,0.f,0.f};
      s = __builtin_amdgcn_mfma_f32_16x16x32_bf16(ka0, qf[0], s, 0, 0, 0);
      s = __builtin_amdgcn_mfma_f32_16x16x32_bf16(ka1, qf[1], s, 0, 0, 0);
      sc[kt] = s;
    }

    // ---- bias (quad-vector gather) + mask + row max; log2 domain ----
    float smax = -3.0e38f;
#pragma unroll
    for (int kt = 0; kt < 4; ++kt) {
      const f32x4 mk = *(const f32x4*)&muk[kt*16 + 4*g];
      int ki0 = k0 + kt*16 + 4*g - R_;          // quad-aligned; quads never straddle 32-grid rows
      int lk  = (ki0 >> 5)*63 + (ki0 & 31);
      int va  = lqc - lk;                        // btgs pos of r=0
      bool okq = ((unsigned)ki0 < 1024u) && qok; // valid-k quad && valid-q lane
      int base = okq ? va : 3;                   // invalid -> btgs[0..3]=0
      f32x4 bv;                                  // bv[3-r] = bias for element r
      bv[0] = btgs[base-3]; bv[1] = btgs[base-2];
      bv[2] = btgs[base-1]; bv[3] = btgs[base];
      bool maskq = (ki0 < 1024);                 // ki0>=1024 -> beyond N_: -inf
      f32x4 s = sc[kt];
#pragma unroll
      for (int r = 0; r < 4; ++r) {
        float val = s[r]*SCL + (muq_c + mk[r]) * bv[3-r];
        val = maskq ? val : -3.0e38f;
        s[r] = val;
        smax = fmaxf(smax, val);
      }
      sc[kt] = s;
    }
    smax = fmaxf(smax, __shfl_xor(smax, 16));
    smax = fmaxf(smax, __shfl_xor(smax, 32));

    // ---- defer-rescale (skip when max unchanged) ----
    if (__any(smax > mrun)) {
      float mnew = fmaxf(mrun, smax);
      float corr = exp2_fast(mrun - mnew);
      lrun *= corr;
#pragma unroll
      for (int r = 0; r < 4; ++r) {
        float cr = __shfl(corr, 20*g + r);       // lane with c == 4g+r
#pragma unroll
        for (int dt = 0; dt < 4; ++dt) O[dt][r] *= cr;
      }
      mrun = mnew;
    }

    // ---- exp2, P->LDS (RNE bf16), row sum ----
    float psum = 0.f;
#pragma unroll
    for (int kt = 0; kt < 4; ++kt) {
      f32x4 s = sc[kt];
      float p0 = exp2_fast(s[0] - mrun), p1 = exp2_fast(s[1] - mrun);
      float p2 = exp2_fast(s[2] - mrun), p3 = exp2_fast(s[3] - mrun);
      psum += (p0 + p1) + (p2 + p3);
      unsigned w0 = pkbf(p0, p1), w1 = pkbf(p2, p3);
      *(u32x2*)&Plds[w][c*64 + ((kt*16 + 4*g) ^ ((c & 7) << 3))] = (u32x2){w0, w1};
    }
    psum += __shfl_xor(psum, 16);
    psum += __shfl_xor(psum, 32);
    lrun += psum;

    // ---- PV: O += P @ V (compiler orders Plds write->read via lgkmcnt) ----
#pragma unroll
    for (int half = 0; half < 2; ++half) {
      bf16x8 pf = *(const bf16x8*)&Plds[w][c*64 + ((half*32 + g*8) ^ ((c & 7) << 3))];
#pragma unroll
      for (int dt = 0; dt < 4; ++dt) {
        int d = dt*16 + c;
        bf16x8 vf = *(const bf16x8*)&Vlds[d*64 + ((half*32 + g*8) ^ ((d & 7) << 3))];
        O[dt] = __builtin_amdgcn_mfma_f32_16x16x32_bf16(pf, vf, O[dt], 0, 0, 0);
      }
    }
  }

  // ---- epilogue: normalize + store f32 ----
  float rlv = 1.f / lrun;
#pragma unroll
  for (int r = 0; r < 4; ++r) {
    float lr = __shfl(rlv, 20*g + r);
    int qo = q0 + 16*w + 4*g + r;
    if (qo < N_) {
      float* ob = outg + ((size_t)bh*N_ + qo)*D_ + c;
#pragma unroll
      for (int dt = 0; dt < 4; ++dt) ob[dt*16] = O[dt][r] * lr;
    }
  }
}

extern "C" void kernel_launch(void* const* d_in, const int* in_sizes, int n_in,
                              void* d_out, int out_size, void* d_ws, size_t ws_size,
                              hipStream_t stream) {
  const float* q     = (const float*)d_in[0];
  const float* k     = (const float*)d_in[1];
  const float* v     = (const float*)d_in[2];
  const float* mu    = (const float*)d_in[3];
  const float* rel   = (const float*)d_in[4];
  const float* W1    = (const float*)d_in[5];
  const float* b1    = (const float*)d_in[6];
  const float* W2    = (const float*)d_in[7];
  const float* gamma = (const float*)d_in[8];
  // d_in[9] idx_table unused: index computed analytically in-kernel.
  float* bt = (float*)d_ws;  // [H][L] = 190 KB scratch

  bt_kernel<<<dim3((L_ + 255)/256), dim3(256), 0, stream>>>(rel, W1, b1, W2, bt);
  attn_kernel<<<dim3(NWG_), dim3(256), 0, stream>>>(q, k, v, mu, gamma, bt,
                                                    (float*)d_out);
}

// Round 6
// 68.119 us; speedup vs baseline: 2.1971x; 1.2117x over previous
//
#include <hip/hip_runtime.h>

#define B_ 4
#define H_ 12
#define N_ 1028
#define D_ 64
#define R_ 4
#define L_ 3969
#define HID_ 32
#define KBLK 64
#define NT_ 17          // k-tiles of 64
#define NBH_ (B_*H_)    // 48
// v1 (fallback) geometry
#define QBLK1 64
#define NWG1 (NBH_*NT_) // 816
// v2 geometry
#define QBLK2 128
#define NQT2 9          // ceil(1028/128)
#define NWG2 (NBH_*NQT2) // 432 = 8*54
#define MUTP 1088       // padded mut row (17*64)
#define LOG2E 1.4426950408889634f
#define SCL1 (0.125f*LOG2E)

typedef __attribute__((ext_vector_type(8))) short bf16x8;
typedef __attribute__((ext_vector_type(4))) float f32x4;
typedef __attribute__((ext_vector_type(2))) unsigned int u32x2;
typedef __attribute__((ext_vector_type(4))) unsigned int u32x4;
typedef __attribute__((address_space(3))) unsigned int lds_u32;
typedef const __attribute__((address_space(1))) unsigned int glb_u32;

// RNE bf16 pair pack via HW cvt: lo -> low16, hi -> high16
__device__ __forceinline__ unsigned pkbf(float lo, float hi) {
  unsigned r;
  asm("v_cvt_pk_bf16_f32 %0, %1, %2" : "=v"(r) : "v"(lo), "v"(hi));
  return r;
}
__device__ __forceinline__ float exp2_fast(float x) {
  float r; asm("v_exp_f32 %0, %1" : "=v"(r) : "v"(x)); return r;
}
__device__ __forceinline__ float sgnlog1p(float x) {
  float t = log1pf(fabsf(x));
  return (x > 0.f) ? t : ((x < 0.f) ? -t : 0.f);
}

// ---- tiny MLP: bt[h][l] ----
__global__ void bt_kernel(const float* __restrict__ rel, const float* __restrict__ W1,
                          const float* __restrict__ b1, const float* __restrict__ W2,
                          float* __restrict__ bt) {
  int l = blockIdx.x * 256 + threadIdx.x;
  if (l >= L_) return;
  float r0 = rel[2*l], r1 = rel[2*l+1];
  float hid[HID_];
#pragma unroll
  for (int j = 0; j < HID_; ++j) {
    float x = W1[2*j]*r0 + W1[2*j+1]*r1 + b1[j];
    hid[j] = 0.5f * x * (1.f + erff(x * 0.70710678118654752f));
  }
#pragma unroll
  for (int h = 0; h < H_; ++h) {
    float acc = 0.f;
#pragma unroll
    for (int j = 0; j < HID_; ++j) acc += W2[h*HID_+j]*hid[j];
    bt[h*L_ + l] = acc;
  }
}

// ---- prep: K/V f32 -> bf16 swizzled LDS tile images in scratch; mu_k -> sgnlog1p ----
// per (bh,t): 8192 shorts = [K image 4096 | V^T image 4096], exactly the LDS layout.
__global__ __launch_bounds__(256) void prep_kernel(
    const float* __restrict__ kg, const float* __restrict__ vg,
    const float* __restrict__ mug, float* __restrict__ mut,
    unsigned short* __restrict__ kv) {
  const int t  = blockIdx.x;
  const int bh = blockIdx.y;
  const int b  = bh / H_, h = bh - b*H_;
  const int tid = threadIdx.x;
  const int k0 = t * KBLK;
  const float* kb = kg + (size_t)bh*N_*D_;
  const float* vb = vg + (size_t)bh*N_*D_;
  unsigned short* Ko = kv + (size_t)(bh*NT_ + t)*8192;
  unsigned short* Vo = Ko + 4096;

  const int kcb = tid >> 4, d4 = (tid & 15) * 4;
#pragma unroll
  for (int i = 0; i < 4; ++i) {
    int kc = kcb + i*16;
    int kr = k0 + kc; if (kr >= N_) kr = N_-1;
    f32x4 a = *(const f32x4*)(kb + (size_t)kr*D_ + d4);
    *(u32x2*)&Ko[kc*64 + (d4 ^ ((kc & 7) << 3))] = (u32x2){pkbf(a[0],a[1]), pkbf(a[2],a[3])};
  }
  const int vd0 = (tid & 15) * 4, vkc0 = (tid >> 4) * 4;
  f32x4 r[4];
#pragma unroll
  for (int i = 0; i < 4; ++i) {
    int kr = k0 + vkc0 + i; if (kr >= N_) kr = N_-1;
    r[i] = *(const f32x4*)(vb + (size_t)kr*D_ + vd0);
  }
#pragma unroll
  for (int j = 0; j < 4; ++j) {
    int d = vd0 + j;
    *(u32x2*)&Vo[d*64 + (vkc0 ^ ((d & 7) << 3))] = (u32x2){pkbf(r[0][j],r[1][j]), pkbf(r[2][j],r[3][j])};
  }
  if (tid < KBLK) {
    int n = k0 + tid; int nc = n < N_ ? n : N_-1;
    mut[bh*MUTP + n] = sgnlog1p(mug[((size_t)b*2*H_ + H_ + h)*N_ + nc]);
  }
}

// ---- attn v2: 512 thr (8 waves), QBLK=128, dbuf KV via global_load_lds ----
__global__ __launch_bounds__(512, 4) void attn2_kernel(
    const float* __restrict__ qg, const float* __restrict__ mug,
    const float* __restrict__ gammag, const float* __restrict__ btg_g,
    const float* __restrict__ mut, const unsigned short* __restrict__ kv,
    float* __restrict__ outg)
{
  __shared__ __align__(16) float btgs[L_ + 4];
  __shared__ __align__(16) unsigned short KV[2][8192];   // [p][0..4095]=K img, [4096..]=V img
  __shared__ __align__(16) unsigned short Plds[8][1024]; // per-wave P [qr][kc]

  const int tid  = threadIdx.x;
  const int w    = tid >> 6;
  const int lane = tid & 63;
  const int g    = lane >> 4;
  const int c    = lane & 15;

  const int orig = blockIdx.x;                   // 432 = 8 x 54 bijective
  const int wg   = (orig & 7) * (NWG2/8) + (orig >> 3);
  const int bh   = wg / NQT2;
  const int qt   = wg - bh * NQT2;
  const int b    = bh / H_;
  const int h    = bh - b * H_;
  const int q0   = qt * QBLK2;

  const float gam  = 1.f / (1.f + __expf(-gammag[h]));
  const float gscl = gam * LOG2E;
  for (int i = tid; i < L_; i += 512) btgs[4 + i] = gscl * btg_g[h*L_ + i];
  if (tid < 4) btgs[tid] = 0.f;

  // Q fragments: 0.125*log2e folded pre-quantization
  const int qrow = q0 + 16*w + c;
  const int qrc  = qrow < N_ ? qrow : N_-1;
  const float* qb = qg + ((size_t)bh*N_ + qrc)*D_;
  bf16x8 qf[2];
#pragma unroll
  for (int ch = 0; ch < 2; ++ch) {
    const float* p = qb + ch*32 + g*8;
    f32x4 a0 = *(const f32x4*)p;
    f32x4 a1 = *(const f32x4*)(p + 4);
    u32x4 qw;
    qw[0] = pkbf(a0[0]*SCL1, a0[1]*SCL1); qw[1] = pkbf(a0[2]*SCL1, a0[3]*SCL1);
    qw[2] = pkbf(a1[0]*SCL1, a1[1]*SCL1); qw[3] = pkbf(a1[2]*SCL1, a1[3]*SCL1);
    qf[ch] = __builtin_bit_cast(bf16x8, qw);
  }
  const float muq_c = (qrow < N_) ? sgnlog1p(mug[((size_t)b*2*H_ + h)*N_ + qrow]) : 0.f;
  const int  qi  = qrow - R_;
  const bool qok = (qi >= 0) && (qrow < N_);
  const int  qy  = qi >> 5, qx = qi & 31;
  const int  lqc = qy*63 + qx + 1988;

  const unsigned short* kvb = kv + (size_t)bh*NT_*8192;
  const float* mt = mut + bh*MUTP;

  auto issue = [&](int tt, int p) {
    const char* src = (const char*)(kvb + (size_t)tt*8192);
    char* dst = (char*)&KV[p][0];
    const int off = w << 11;                     // wave copies 2KB
#pragma unroll
    for (int j = 0; j < 2; ++j) {
      int o = off + j*1024;
      __builtin_amdgcn_global_load_lds((glb_u32*)(src + o + lane*16),
                                       (lds_u32*)(dst + o), 16, 0, 0);
    }
  };

  float mrun = -3.0e38f, lrun = 0.f;
  f32x4 O[4];
#pragma unroll
  for (int dt = 0; dt < 4; ++dt) O[dt] = (f32x4){0.f,0.f,0.f,0.f};

  issue(0, 0);

  for (int t = 0; t < NT_; ++t) {
    const int k0 = t * KBLK;
    const int p  = t & 1;
    asm volatile("s_waitcnt vmcnt(0)" ::: "memory");  // this tile's glds landed
    __syncthreads();

    // mu_k quads for THIS tile — issued before next-tile glds so their wait
    // (vmcnt(2)) doesn't drain the pipeline
    f32x4 mk4[4];
#pragma unroll
    for (int kt = 0; kt < 4; ++kt) mk4[kt] = *(const f32x4*)&mt[k0 + kt*16 + 4*g];
    __builtin_amdgcn_sched_barrier(0);
    if (t + 1 < NT_) issue(t + 1, p ^ 1);

    const unsigned short* Kl = &KV[p][0];
    const unsigned short* Vl = &KV[p][4096];

    // ---- S^T: 4 kc-subtiles x 2 d-chunks ----
    f32x4 sc[4];
#pragma unroll
    for (int kt = 0; kt < 4; ++kt) {
      int row = kt*16 + c;
      int sw  = (row & 7) << 3;
      bf16x8 ka0 = *(const bf16x8*)&Kl[row*64 + ((g*8) ^ sw)];
      bf16x8 ka1 = *(const bf16x8*)&Kl[row*64 + ((32 + g*8) ^ sw)];
      f32x4 s = (f32x4){0.f,0.f,0.f,0.f};
      s = __builtin_amdgcn_mfma_f32_16x16x32_bf16(ka0, qf[0], s, 0, 0, 0);
      s = __builtin_amdgcn_mfma_f32_16x16x32_bf16(ka1, qf[1], s, 0, 0, 0);
      sc[kt] = s;
    }

    // ---- bias (quad gather) + mask + row max ----
    float smax = -3.0e38f;
#pragma unroll
    for (int kt = 0; kt < 4; ++kt) {
      const f32x4 mk = mk4[kt];
      int ki0 = k0 + kt*16 + 4*g - R_;
      int lk  = (ki0 >> 5)*63 + (ki0 & 31);
      int va  = lqc - lk;
      bool okq = ((unsigned)ki0 < 1024u) && qok;
      int base = okq ? va : 3;
      f32x4 bv;
      bv[0] = btgs[base-3]; bv[1] = btgs[base-2];
      bv[2] = btgs[base-1]; bv[3] = btgs[base];
      bool maskq = (ki0 < 1024);
      f32x4 s = sc[kt];
#pragma unroll
      for (int r = 0; r < 4; ++r) {
        float val = s[r] + (muq_c + mk[r]) * bv[3-r];
        val = maskq ? val : -3.0e38f;
        s[r] = val;
        smax = fmaxf(smax, val);
      }
      sc[kt] = s;
    }
    smax = fmaxf(smax, __shfl_xor(smax, 16));
    smax = fmaxf(smax, __shfl_xor(smax, 32));

    if (__any(smax > mrun)) {
      float mnew = fmaxf(mrun, smax);
      float corr = exp2_fast(mrun - mnew);
      lrun *= corr;
#pragma unroll
      for (int r = 0; r < 4; ++r) {
        float cr = __shfl(corr, 20*g + r);
#pragma unroll
        for (int dt = 0; dt < 4; ++dt) O[dt][r] *= cr;
      }
      mrun = mnew;
    }

    // ---- exp2, P->LDS, row sum ----
    float psum = 0.f;
#pragma unroll
    for (int kt = 0; kt < 4; ++kt) {
      f32x4 s = sc[kt];
      float p0 = exp2_fast(s[0] - mrun), p1 = exp2_fast(s[1] - mrun);
      float p2 = exp2_fast(s[2] - mrun), p3 = exp2_fast(s[3] - mrun);
      psum += (p0 + p1) + (p2 + p3);
      *(u32x2*)&Plds[w][c*64 + ((kt*16 + 4*g) ^ ((c & 7) << 3))] = (u32x2){pkbf(p0,p1), pkbf(p2,p3)};
    }
    psum += __shfl_xor(psum, 16);
    psum += __shfl_xor(psum, 32);
    lrun += psum;

    // ---- PV ----
#pragma unroll
    for (int half = 0; half < 2; ++half) {
      bf16x8 pf = *(const bf16x8*)&Plds[w][c*64 + ((half*32 + g*8) ^ ((c & 7) << 3))];
#pragma unroll
      for (int dt = 0; dt < 4; ++dt) {
        int d = dt*16 + c;
        bf16x8 vf = *(const bf16x8*)&Vl[d*64 + ((half*32 + g*8) ^ ((d & 7) << 3))];
        O[dt] = __builtin_amdgcn_mfma_f32_16x16x32_bf16(pf, vf, O[dt], 0, 0, 0);
      }
    }
  }

  float rlv = 1.f / lrun;
#pragma unroll
  for (int r = 0; r < 4; ++r) {
    float lr = __shfl(rlv, 20*g + r);
    int qo = q0 + 16*w + 4*g + r;
    if (qo < N_) {
      float* ob = outg + ((size_t)bh*N_ + qo)*D_ + c;
#pragma unroll
      for (int dt = 0; dt < 4; ++dt) ob[dt*16] = O[dt][r] * lr;
    }
  }
}

// ---- fallback (round-5, proven): used only if ws_size too small ----
__global__ __launch_bounds__(256, 4) void attn1_kernel(
    const float* __restrict__ qg, const float* __restrict__ kg_,
    const float* __restrict__ vg, const float* __restrict__ mug,
    const float* __restrict__ gammag, const float* __restrict__ btg_g,
    float* __restrict__ outg)
{
  __shared__ __align__(16) float btgs[L_ + 4];
  __shared__ __align__(16) unsigned short Klds[KBLK*64];
  __shared__ __align__(16) unsigned short Vlds[64*KBLK];
  __shared__ __align__(16) unsigned short Plds[4][16*64];
  __shared__ __align__(16) float muk[KBLK];

  const int tid  = threadIdx.x;
  const int w    = tid >> 6;
  const int lane = tid & 63;
  const int g    = lane >> 4;
  const int c    = lane & 15;

  const int orig = blockIdx.x;
  const int wg   = (orig & 7) * (NWG1 / 8) + (orig >> 3);
  const int bh   = wg / NT_;
  const int qt   = wg - bh * NT_;
  const int b    = bh / H_;
  const int h    = bh - b * H_;
  const int q0   = qt * QBLK1;

  const float gam  = 1.f / (1.f + __expf(-gammag[h]));
  const float gscl = gam * LOG2E;
  for (int i = tid; i < L_; i += 256) btgs[4 + i] = gscl * btg_g[h*L_ + i];
  if (tid < 4) btgs[tid] = 0.f;

  const float* qb   = qg  + (size_t)bh*N_*D_;
  const float* kb   = kg_ + (size_t)bh*N_*D_;
  const float* vb   = vg  + (size_t)bh*N_*D_;
  const float* mukp = mug + ((size_t)b*2*H_ + H_ + h)*N_;

  const int qrow = q0 + 16*w + c;
  const int qrc  = qrow < N_ ? qrow : N_-1;
  bf16x8 qf[2];
#pragma unroll
  for (int ch = 0; ch < 2; ++ch) {
    const float* p = qb + (size_t)qrc*D_ + ch*32 + g*8;
    f32x4 a0 = *(const f32x4*)p;
    f32x4 a1 = *(const f32x4*)(p + 4);
    u32x4 qw;
    qw[0] = pkbf(a0[0]*SCL1, a0[1]*SCL1); qw[1] = pkbf(a0[2]*SCL1, a0[3]*SCL1);
    qw[2] = pkbf(a1[0]*SCL1, a1[1]*SCL1); qw[3] = pkbf(a1[2]*SCL1, a1[3]*SCL1);
    qf[ch] = __builtin_bit_cast(bf16x8, qw);
  }
  const float muq_c = (qrow < N_) ? sgnlog1p(mug[((size_t)b*2*H_ + h)*N_ + qrow]) : 0.f;
  const int  qi  = qrow - R_;
  const bool qok = (qi >= 0) && (qrow < N_);
  const int  qy  = qi >> 5, qx = qi & 31;
  const int  lqc = qy*63 + qx + 1988;

  const int kcb  = tid >> 4;
  const int d4   = (tid & 15) * 4;
  const int vd0  = (tid & 15) * 4;
  const int vkc0 = (tid >> 4) * 4;

  f32x4 kpre[4], vpre[4];
  float mupre = 0.f;
  auto issue = [&](int tt) {
    const int k0n = tt * KBLK;
#pragma unroll
    for (int i = 0; i < 4; ++i) {
      int kr = k0n + kcb + i*16; if (kr >= N_) kr = N_-1;
      kpre[i] = *(const f32x4*)(kb + (size_t)kr*D_ + d4);
    }
#pragma unroll
    for (int i = 0; i < 4; ++i) {
      int kr = k0n + vkc0 + i; if (kr >= N_) kr = N_-1;
      vpre[i] = *(const f32x4*)(vb + (size_t)kr*D_ + vd0);
    }
    if (tid < KBLK) {
      int kr = k0n + tid; if (kr >= N_) kr = N_-1;
      mupre = mukp[kr];
    }
  };

  float mrun = -3.0e38f, lrun = 0.f;
  f32x4 O[4];
#pragma unroll
  for (int dt = 0; dt < 4; ++dt) O[dt] = (f32x4){0.f,0.f,0.f,0.f};

  issue(0);

  for (int t = 0; t < NT_; ++t) {
    const int k0 = t * KBLK;
    __syncthreads();
#pragma unroll
    for (int i = 0; i < 4; ++i) {
      int kc = kcb + i*16;
      *(u32x2*)&Klds[kc*64 + (d4 ^ ((kc & 7) << 3))] =
          (u32x2){pkbf(kpre[i][0], kpre[i][1]), pkbf(kpre[i][2], kpre[i][3])};
    }
#pragma unroll
    for (int j = 0; j < 4; ++j) {
      int d = vd0 + j;
      *(u32x2*)&Vlds[d*64 + (vkc0 ^ ((d & 7) << 3))] =
          (u32x2){pkbf(vpre[0][j], vpre[1][j]), pkbf(vpre[2][j], vpre[3][j])};
    }
    if (tid < KBLK) muk[tid] = sgnlog1p(mupre);
    __syncthreads();
    if (t + 1 < NT_) issue(t + 1);

    f32x4 sc[4];
#pragma unroll
    for (int kt = 0; kt < 4; ++kt) {
      int row = kt*16 + c;
      int sw  = (row & 7) << 3;
      bf16x8 ka0 = *(const bf16x8*)&Klds[row*64 + ((g*8) ^ sw)];
      bf16x8 ka1 = *(const bf16x8*)&Klds[row*64 + ((32 + g*8) ^ sw)];
      f32x4 s = (f32x4){0.f,0.f,0.f,0.f};
      s = __builtin_amdgcn_mfma_f32_16x16x32_bf16(ka0, qf[0], s, 0, 0, 0);
      s = __builtin_amdgcn_mfma_f32_16x16x32_bf16(ka1, qf[1], s, 0, 0, 0);
      sc[kt] = s;
    }

    float smax = -3.0e38f;
#pragma unroll
    for (int kt = 0; kt < 4; ++kt) {
      const f32x4 mk = *(const f32x4*)&muk[kt*16 + 4*g];
      int ki0 = k0 + kt*16 + 4*g - R_;
      int lk  = (ki0 >> 5)*63 + (ki0 & 31);
      int va  = lqc - lk;
      bool okq = ((unsigned)ki0 < 1024u) && qok;
      int base = okq ? va : 3;
      f32x4 bv;
      bv[0] = btgs[base-3]; bv[1] = btgs[base-2];
      bv[2] = btgs[base-1]; bv[3] = btgs[base];
      bool maskq = (ki0 < 1024);
      f32x4 s = sc[kt];
#pragma unroll
      for (int r = 0; r < 4; ++r) {
        float val = s[r] + (muq_c + mk[r]) * bv[3-r];
        val = maskq ? val : -3.0e38f;
        s[r] = val;
        smax = fmaxf(smax, val);
      }
      sc[kt] = s;
    }
    smax = fmaxf(smax, __shfl_xor(smax, 16));
    smax = fmaxf(smax, __shfl_xor(smax, 32));

    if (__any(smax > mrun)) {
      float mnew = fmaxf(mrun, smax);
      float corr = exp2_fast(mrun - mnew);
      lrun *= corr;
#pragma unroll
      for (int r = 0; r < 4; ++r) {
        float cr = __shfl(corr, 20*g + r);
#pragma unroll
        for (int dt = 0; dt < 4; ++dt) O[dt][r] *= cr;
      }
      mrun = mnew;
    }

    float psum = 0.f;
#pragma unroll
    for (int kt = 0; kt < 4; ++kt) {
      f32x4 s = sc[kt];
      float p0 = exp2_fast(s[0] - mrun), p1 = exp2_fast(s[1] - mrun);
      float p2 = exp2_fast(s[2] - mrun), p3 = exp2_fast(s[3] - mrun);
      psum += (p0 + p1) + (p2 + p3);
      *(u32x2*)&Plds[w][c*64 + ((kt*16 + 4*g) ^ ((c & 7) << 3))] = (u32x2){pkbf(p0,p1), pkbf(p2,p3)};
    }
    psum += __shfl_xor(psum, 16);
    psum += __shfl_xor(psum, 32);
    lrun += psum;

#pragma unroll
    for (int half = 0; half < 2; ++half) {
      bf16x8 pf = *(const bf16x8*)&Plds[w][c*64 + ((half*32 + g*8) ^ ((c & 7) << 3))];
#pragma unroll
      for (int dt = 0; dt < 4; ++dt) {
        int d = dt*16 + c;
        bf16x8 vf = *(const bf16x8*)&Vlds[d*64 + ((half*32 + g*8) ^ ((d & 7) << 3))];
        O[dt] = __builtin_amdgcn_mfma_f32_16x16x32_bf16(pf, vf, O[dt], 0, 0, 0);
      }
    }
  }

  float rlv = 1.f / lrun;
#pragma unroll
  for (int r = 0; r < 4; ++r) {
    float lr = __shfl(rlv, 20*g + r);
    int qo = q0 + 16*w + 4*g + r;
    if (qo < N_) {
      float* ob = outg + ((size_t)bh*N_ + qo)*D_ + c;
#pragma unroll
      for (int dt = 0; dt < 4; ++dt) ob[dt*16] = O[dt][r] * lr;
    }
  }
}

extern "C" void kernel_launch(void* const* d_in, const int* in_sizes, int n_in,
                              void* d_out, int out_size, void* d_ws, size_t ws_size,
                              hipStream_t stream) {
  const float* q     = (const float*)d_in[0];
  const float* k     = (const float*)d_in[1];
  const float* v     = (const float*)d_in[2];
  const float* mu    = (const float*)d_in[3];
  const float* rel   = (const float*)d_in[4];
  const float* W1    = (const float*)d_in[5];
  const float* b1    = (const float*)d_in[6];
  const float* W2    = (const float*)d_in[7];
  const float* gamma = (const float*)d_in[8];

  float* bt = (float*)d_ws;                               // H*L f32
  float* mut = bt + H_*L_;                                // 48*1088 f32
  unsigned short* kvimg = (unsigned short*)(mut + NBH_*MUTP); // 48*17*8192 shorts
  const size_t need = (size_t)H_*L_*4 + (size_t)NBH_*MUTP*4 + (size_t)NBH_*NT_*8192*2;

  bt_kernel<<<dim3((L_ + 255)/256), dim3(256), 0, stream>>>(rel, W1, b1, W2, bt);
  if (ws_size >= need) {
    prep_kernel<<<dim3(NT_, NBH_), dim3(256), 0, stream>>>(k, v, mu, mut, kvimg);
    attn2_kernel<<<dim3(NWG2), dim3(512), 0, stream>>>(q, mu, gamma, bt, mut, kvimg,
                                                       (float*)d_out);
  } else {
    attn1_kernel<<<dim3(NWG1), dim3(256), 0, stream>>>(q, k, v, mu, gamma, bt,
                                                       (float*)d_out);
  }
}

// Round 7
// 61.632 us; speedup vs baseline: 2.4283x; 1.1052x over previous
//
#include <hip/hip_runtime.h>

#define B_ 4
#define H_ 12
#define N_ 1028
#define D_ 64
#define R_ 4
#define L_ 3969
#define HID_ 32
#define KBLK 64
#define NT_ 17            // k-tiles of 64
#define NBH_ (B_*H_)      // 48
#define QBLK 256
#define NQT 5             // ceil(1028/256)
#define NWG (NBH_*NQT)    // 240 = 8 * 30
#define MUTP 1088         // padded mut row (17*64)
#define LOG2E 1.4426950408889634f
#define SCL1 (0.125f*LOG2E)

typedef __attribute__((ext_vector_type(8)))  short bf16x8;
typedef __attribute__((ext_vector_type(2)))  float f32x2;
typedef __attribute__((ext_vector_type(4)))  float f32x4;
typedef __attribute__((ext_vector_type(16))) float f32x16;
typedef __attribute__((ext_vector_type(2)))  unsigned int u32x2;
typedef __attribute__((ext_vector_type(4)))  unsigned int u32x4;

// RNE bf16 pair pack via HW cvt: lo -> low16, hi -> high16
__device__ __forceinline__ unsigned pkbf(float lo, float hi) {
  unsigned r;
  asm("v_cvt_pk_bf16_f32 %0, %1, %2" : "=v"(r) : "v"(lo), "v"(hi));
  return r;
}
__device__ __forceinline__ float exp2_fast(float x) {
  float r; asm("v_exp_f32 %0, %1" : "=v"(r) : "v"(x)); return r;
}
__device__ __forceinline__ float sgnlog1p(float x) {
  float t = log1pf(fabsf(x));
  return (x > 0.f) ? t : ((x < 0.f) ? -t : 0.f);
}

// ---- fused: bt MLP table (blocks 0..15) + mu_k sgnlog1p transform (rest) ----
__global__ __launch_bounds__(256) void btmu_kernel(
    const float* __restrict__ rel, const float* __restrict__ W1,
    const float* __restrict__ b1, const float* __restrict__ W2,
    const float* __restrict__ mug, float* __restrict__ bt,
    float* __restrict__ mut) {
  const int blk = blockIdx.x;
  const int tid = threadIdx.x;
  if (blk < 16) {
    int l = blk * 256 + tid;
    if (l >= L_) return;
    float r0 = rel[2*l], r1 = rel[2*l+1];
    float hid[HID_];
#pragma unroll
    for (int j = 0; j < HID_; ++j) {
      float x = W1[2*j]*r0 + W1[2*j+1]*r1 + b1[j];
      hid[j] = 0.5f * x * (1.f + erff(x * 0.70710678118654752f));
    }
#pragma unroll
    for (int h = 0; h < H_; ++h) {
      float acc = 0.f;
#pragma unroll
      for (int j = 0; j < HID_; ++j) acc += W2[h*HID_+j]*hid[j];
      bt[h*L_ + l] = acc;
    }
  } else {
    int idx = (blk - 16) * 256 + tid;           // over 48*1088
    if (idx >= NBH_*MUTP) return;
    int bh = idx / MUTP, n = idx - bh*MUTP;
    int b = bh / H_, h = bh - b*H_;
    int nc = n < N_ ? n : N_-1;
    mut[bh*MUTP + n] = sgnlog1p(mug[((size_t)b*2*H_ + H_ + h)*N_ + nc]);
  }
}

// ---- flash attention, 32x32x16 MFMA, 8 waves x 32 q-rows, inline staging ----
// S^T = mfma(A=K, B=Q): D col=lane&31=q, row=(reg&3)+8(reg>>2)+4hi = kc (+32/blk).
// P stays in registers: PV k-slot map defined as (e&3)+8(e>>2)+4hi, matching the
// D kc-pattern; V^T staged with kc bits 2<->3 swapped so b128 reads align.
// O^T = mfma(A=V^T, B=P^T): D col=q -> softmax state fully lane-local.
__global__ __launch_bounds__(512, 2) void attn_kernel(
    const float* __restrict__ qg, const float* __restrict__ kg_,
    const float* __restrict__ vg, const float* __restrict__ mug,
    const float* __restrict__ gammag, const float* __restrict__ btg_g,
    const float* __restrict__ mut, float* __restrict__ outg)
{
  __shared__ __align__(16) float btgs[L_ + 4];            // [0..3]=0 sentinel
  __shared__ __align__(16) unsigned short Kl[2][64*64];   // [kc][d] bf16, granule^=(kc&7)
  __shared__ __align__(16) unsigned short Vl[2][64*64];   // V^T [d][kc'] bf16 (kc bits2<->3), granule^=(d&7)

  const int tid  = threadIdx.x;
  const int w    = tid >> 6;
  const int lane = tid & 63;
  const int hi   = lane >> 5;
  const int c    = lane & 31;

  // bijective XCD swizzle: 240 = 8 x 30
  const int orig = blockIdx.x;
  const int wg   = (orig & 7) * (NWG/8) + (orig >> 3);
  const int bh   = wg / NQT;
  const int qt   = wg - bh * NQT;
  const int b    = bh / H_;
  const int h    = bh - b * H_;
  const int q0   = qt * QBLK;

  const float gam  = 1.f / (1.f + __expf(-gammag[h]));
  const float gscl = gam * LOG2E;
  for (int i = tid; i < L_; i += 512) btgs[4 + i] = gscl * btg_g[h*L_ + i];
  if (tid < 4) btgs[tid] = 0.f;

  const float* qb = qg  + (size_t)bh*N_*D_;
  const float* kb = kg_ + (size_t)bh*N_*D_;
  const float* vb = vg  + (size_t)bh*N_*D_;
  const float* mt = mut + bh*MUTP;

  // Q fragments: qf[m] = Q[qrow][d = 16m + 8hi .. +7] * SCL1
  const int qrow = q0 + 32*w + c;
  const int qrc  = qrow < N_ ? qrow : N_-1;
  bf16x8 qf[4];
#pragma unroll
  for (int m = 0; m < 4; ++m) {
    const float* p = qb + (size_t)qrc*D_ + 16*m + 8*hi;
    f32x4 a0 = *(const f32x4*)p;
    f32x4 a1 = *(const f32x4*)(p + 4);
    u32x4 qw;
    qw[0] = pkbf(a0[0]*SCL1, a0[1]*SCL1); qw[1] = pkbf(a0[2]*SCL1, a0[3]*SCL1);
    qw[2] = pkbf(a1[0]*SCL1, a1[1]*SCL1); qw[3] = pkbf(a1[2]*SCL1, a1[3]*SCL1);
    qf[m] = __builtin_bit_cast(bf16x8, qw);
  }
  const float muq_c = (qrow < N_) ? sgnlog1p(mug[((size_t)b*2*H_ + h)*N_ + qrow]) : 0.f;
  const int  qi  = qrow - R_;
  const bool qok = (qi >= 0) && (qrow < N_);
  const int  qy  = qi >> 5, qx = qi & 31;
  const int  lqc = qy*63 + qx + 1988;     // btgs base (+4 sentinel, +1984 geom)

  // staging thread roles
  const int skr = tid >> 3;               // K: row 0..63
  const int so  = tid & 7;                // K: 16B granule 0..7
  const int vkc0 = (tid & 15) * 4;        // V: kc quad
  const int vdp  = (tid >> 4) * 2;        // V: d pair
  const int vkc0p = ((vkc0 >> 1) & 4) | ((vkc0 << 1) & 8) | (vkc0 & 48); // bits2<->3

  f32x4 ka0_, ka1_;                       // K prefetch (8 f32)
  f32x2 vpre[4];                          // V prefetch (8 f32)
  auto issue = [&](int tt) {
    const int k0n = tt * KBLK;
    {
      int kr = k0n + skr; if (kr >= N_) kr = N_-1;
      const float* p = kb + (size_t)kr*D_ + 8*so;
      ka0_ = *(const f32x4*)p;
      ka1_ = *(const f32x4*)(p + 4);
    }
#pragma unroll
    for (int i = 0; i < 4; ++i) {
      int kr = k0n + vkc0 + i; if (kr >= N_) kr = N_-1;
      vpre[i] = *(const f32x2*)(vb + (size_t)kr*D_ + vdp);
    }
  };

  float mrun = -3.0e38f, lrun = 0.f;
  f32x16 Ot[2];
#pragma unroll
  for (int blk = 0; blk < 2; ++blk)
#pragma unroll
    for (int r = 0; r < 16; ++r) Ot[blk][r] = 0.f;

  issue(0);

  for (int t = 0; t < NT_; ++t) {
    const int k0 = t * KBLK;
    const int p  = t & 1;
    // ---- write staged regs -> LDS buf p (auto vmcnt waits on pre-regs) ----
    {
      u32x4 kw;
      kw[0] = pkbf(ka0_[0], ka0_[1]); kw[1] = pkbf(ka0_[2], ka0_[3]);
      kw[2] = pkbf(ka1_[0], ka1_[1]); kw[3] = pkbf(ka1_[2], ka1_[3]);
      *(u32x4*)&Kl[p][skr*64 + ((8*so) ^ ((skr & 7) << 3))] = kw;
#pragma unroll
      for (int dd = 0; dd < 2; ++dd) {
        int d = vdp + dd;
        u32x2 vw = (u32x2){pkbf(vpre[0][dd], vpre[1][dd]), pkbf(vpre[2][dd], vpre[3][dd])};
        *(u32x2*)&Vl[p][d*64 + (vkc0p ^ ((d & 7) << 3))] = vw;
      }
    }
    if (t + 1 < NT_) issue(t + 1);     // next-tile loads fly across the barrier
    __syncthreads();

    // ---- mu_k quads for this tile (global, L2 — scheduled by compiler) ----
    f32x4 mkv[2][4];
#pragma unroll
    for (int bb = 0; bb < 2; ++bb)
#pragma unroll
      for (int r2 = 0; r2 < 4; ++r2)
        mkv[bb][r2] = *(const f32x4*)&mt[k0 + 32*bb + 8*r2 + 4*hi];

    // ---- S^T: 2 kc-blocks x 4 d-chunks ----
    f32x16 sc[2];
#pragma unroll
    for (int bb = 0; bb < 2; ++bb)
#pragma unroll
      for (int r = 0; r < 16; ++r) sc[bb][r] = 0.f;
    __builtin_amdgcn_s_setprio(1);
#pragma unroll
    for (int m = 0; m < 4; ++m) {
      int sw = (c & 7) << 3;
      bf16x8 ka0 = *(const bf16x8*)&Kl[p][c*64        + ((16*m + 8*hi) ^ sw)];
      bf16x8 ka1 = *(const bf16x8*)&Kl[p][(32+c)*64   + ((16*m + 8*hi) ^ sw)];
      sc[0] = __builtin_amdgcn_mfma_f32_32x32x16_bf16(ka0, qf[m], sc[0], 0, 0, 0);
      sc[1] = __builtin_amdgcn_mfma_f32_32x32x16_bf16(ka1, qf[m], sc[1], 0, 0, 0);
    }
    __builtin_amdgcn_s_setprio(0);

    // ---- bias (quad gather) + mask + row max ----
    float smax = -3.0e38f;
#pragma unroll
    for (int bb = 0; bb < 2; ++bb) {
#pragma unroll
      for (int r2 = 0; r2 < 4; ++r2) {
        const f32x4 mk = mkv[bb][r2];
        int base_kc = 32*bb + 8*r2 + 4*hi;
        int ki0 = k0 + base_kc - R_;
        int lk  = (ki0 >> 5)*63 + (ki0 & 31);
        int va  = lqc - lk;
        bool okq = ((unsigned)ki0 < 1024u) && qok;
        int basep = okq ? va : 3;
        f32x4 bv;                          // bv[3-rr] = bias for element rr
        bv[0] = btgs[basep-3]; bv[1] = btgs[basep-2];
        bv[2] = btgs[basep-1]; bv[3] = btgs[basep];
        bool maskq = (ki0 < 1024);
#pragma unroll
        for (int rr = 0; rr < 4; ++rr) {
          float val = sc[bb][4*r2+rr] + (muq_c + mk[rr]) * bv[3-rr];
          val = maskq ? val : -3.0e38f;
          sc[bb][4*r2+rr] = val;
          smax = fmaxf(smax, val);
        }
      }
    }
    smax = fmaxf(smax, __shfl_xor(smax, 32));

    // ---- defer-rescale (corr is lane-local: q = c for both hi halves) ----
    if (__any(smax > mrun)) {
      float mnew = fmaxf(mrun, smax);
      float corr = exp2_fast(mrun - mnew);
      lrun *= corr;
#pragma unroll
      for (int blk = 0; blk < 2; ++blk)
#pragma unroll
        for (int r = 0; r < 16; ++r) Ot[blk][r] *= corr;
      mrun = mnew;
    }

    // ---- exp2 + row sum (in-place into sc) ----
    float psum = 0.f;
#pragma unroll
    for (int bb = 0; bb < 2; ++bb)
#pragma unroll
      for (int r = 0; r < 16; ++r) {
        float pv = exp2_fast(sc[bb][r] - mrun);
        sc[bb][r] = pv;
        psum += pv;
      }
    psum += __shfl_xor(psum, 32);
    lrun += psum;

    // ---- P fragments: pure cvt_pk, no LDS ----
    u32x4 pa[4];
#pragma unroll
    for (int mm = 0; mm < 4; ++mm) {
      int bb = mm >> 1, s = (mm & 1) * 8;
#pragma unroll
      for (int j = 0; j < 4; ++j)
        pa[mm][j] = pkbf(sc[bb][s + 2*j], sc[bb][s + 2*j + 1]);
    }

    // ---- PV: O^T += V^T · P^T ----
    __builtin_amdgcn_s_setprio(1);
#pragma unroll
    for (int mm = 0; mm < 4; ++mm) {
      bf16x8 pfr = __builtin_bit_cast(bf16x8, pa[mm]);
      int sw = (c & 7) << 3;
      bf16x8 va0 = *(const bf16x8*)&Vl[p][c*64      + ((16*mm + 8*hi) ^ sw)];
      bf16x8 va1 = *(const bf16x8*)&Vl[p][(32+c)*64 + ((16*mm + 8*hi) ^ sw)];
      Ot[0] = __builtin_amdgcn_mfma_f32_32x32x16_bf16(va0, pfr, Ot[0], 0, 0, 0);
      Ot[1] = __builtin_amdgcn_mfma_f32_32x32x16_bf16(va1, pfr, Ot[1], 0, 0, 0);
    }
    __builtin_amdgcn_s_setprio(0);
  }

  // ---- epilogue: normalize + store f32 (O^T: lane q=c, d scattered quads) ----
  float rlv = 1.f / lrun;
  const int qo = q0 + 32*w + c;
  if (qo < N_) {
    float* ob = outg + ((size_t)bh*N_ + qo)*D_;
#pragma unroll
    for (int blk = 0; blk < 2; ++blk)
#pragma unroll
      for (int r2 = 0; r2 < 4; ++r2) {
        int dbase = 8*r2 + 4*hi + 32*blk;
        f32x4 ov;
#pragma unroll
        for (int rr = 0; rr < 4; ++rr) ov[rr] = Ot[blk][4*r2+rr] * rlv;
        *(f32x4*)(ob + dbase) = ov;
      }
  }
}

extern "C" void kernel_launch(void* const* d_in, const int* in_sizes, int n_in,
                              void* d_out, int out_size, void* d_ws, size_t ws_size,
                              hipStream_t stream) {
  const float* q     = (const float*)d_in[0];
  const float* k     = (const float*)d_in[1];
  const float* v     = (const float*)d_in[2];
  const float* mu    = (const float*)d_in[3];
  const float* rel   = (const float*)d_in[4];
  const float* W1    = (const float*)d_in[5];
  const float* b1    = (const float*)d_in[6];
  const float* W2    = (const float*)d_in[7];
  const float* gamma = (const float*)d_in[8];
  // d_in[9] idx_table unused: index computed analytically in-kernel.

  float* bt  = (float*)d_ws;               // H*L f32
  float* mut = bt + H_*L_;                 // 48*1088 f32

  const int mutblocks = (NBH_*MUTP + 255) / 256;   // 204
  btmu_kernel<<<dim3(16 + mutblocks), dim3(256), 0, stream>>>(rel, W1, b1, W2, mu, bt, mut);
  attn_kernel<<<dim3(NWG), dim3(512), 0, stream>>>(q, k, v, mu, gamma, bt, mut,
                                                   (float*)d_out);
}